// Round 6
// baseline (219.216 us; speedup 1.0000x reference)
//
#include <hip/hip_runtime.h>
#include <float.h>

#define BB 128
#define NN 500
#define CC 80
#define NH 6
#define NP 512          // padded N

typedef unsigned long long u64;
typedef unsigned int u32;

// ---------------------------------------------------------------------------
// Mega-kernel: one block (512 threads, 8 waves) per batch does EVERYTHING.
//  P0a: quad-per-row softmax scores/labels for own batch -> LDS + global
//  P0b: quad-per-row max for batch 0 -> keep (redundant per block, LLC-served)
//  P0c: load boxes_start, precompute (x1,x2,w)
//  P1 : fused boxes_next (needs keep)
//  P2 : label-local rank via single fused u8-label/float4-score scan
//       + LDS histogram + wave-0 shuffle prefix -> bucket member lists
//  P3 : wave-per-bucket register greedy (readlane broadcasts + ballot)
//  P4 : coalesced keep_out write (supp indexed by ORIGINAL id - no sort)
// Per-label greedy in label-local (score desc, idx asc) order == reference
// global-order greedy, because suppression only couples same-label pairs.
// ---------------------------------------------------------------------------
__global__ __launch_bounds__(512) void fused_kernel(
    const float* __restrict__ boxes_t,
    const float* __restrict__ pc,
    const float* __restrict__ pb,
    const float* __restrict__ noise,
    const float* __restrict__ fresh,
    const float* __restrict__ ac,
    const int* __restrict__ t_now_p,
    const int* __restrict__ t_next_p,
    float* __restrict__ out_boxes,
    float* __restrict__ out_scores,
    float* __restrict__ out_labels,
    float* __restrict__ out_keep) {

    __shared__ float4 scs4[NP / 4];        // scores (pad -FLT_MAX)
    __shared__ float4 box4u[NP];           // (x1,x2,w,unused) by original id
    __shared__ unsigned char lab8[NP];     // labels u8 (pad 255)
    __shared__ unsigned char keepb[NP];    // batch-0 keep flags
    __shared__ short brank_s[NP];          // label-local rank
    __shared__ short member[NP];           // bucket-ordered original ids
    __shared__ int hist[CC];
    __shared__ int boff[CC];
    __shared__ unsigned char supp[NP];

    const int b = blockIdx.x;
    const int tid = threadIdx.x;
    float* scs = (float*)scs4;

    const int quad = tid >> 2;             // 0..127
    const int q = tid & 3;

    if (tid < CC) hist[tid] = 0;
    supp[tid] = 0;
    if (tid >= NN) { scs[tid] = -FLT_MAX; lab8[tid] = 255; }

    // ---- P0a: own-batch scores/labels (quad per row, 4 passes) ----
    const float4* rowbase = (const float4*)(pc + (size_t)(NH - 1) * BB * NN * CC
                                               + (size_t)b * NN * CC);
#pragma unroll
    for (int pass = 0; pass < 4; ++pass) {
        const int row = pass * 128 + quad;
        if (row < NN) {
            float4 v[5];
#pragma unroll
            for (int k = 0; k < 5; ++k) v[k] = rowbase[(size_t)row * 20 + q + 4 * k];
            float m = v[0].x;
#pragma unroll
            for (int k = 0; k < 5; ++k) {
                m = fmaxf(m, v[k].x); m = fmaxf(m, v[k].y);
                m = fmaxf(m, v[k].z); m = fmaxf(m, v[k].w);
            }
            m = fmaxf(m, __shfl_xor(m, 1));
            m = fmaxf(m, __shfl_xor(m, 2));
            float s = 0.0f;
#pragma unroll
            for (int k = 0; k < 5; ++k) {
                s += expf(v[k].x - m); s += expf(v[k].y - m);
                s += expf(v[k].z - m); s += expf(v[k].w - m);
            }
            s += __shfl_xor(s, 1);
            s += __shfl_xor(s, 2);
            float bv = -FLT_MAX; int bc = 1000;
#pragma unroll
            for (int k = 0; k < 5; ++k) {
                const float* vf = (const float*)&v[k];
#pragma unroll
                for (int j = 0; j < 4; ++j) {
                    int c = (q + 4 * k) * 4 + j;
                    float val = vf[j];
                    if (c < CC - 1 && (val > bv || (val == bv && c < bc))) { bv = val; bc = c; }
                }
            }
#pragma unroll
            for (int off = 1; off < 4; off <<= 1) {
                float ov = __shfl_xor(bv, off);
                int oc = __shfl_xor(bc, off);
                if (ov > bv || (ov == bv && oc < bc)) { bv = ov; bc = oc; }
            }
            if (q == 0) {
                float sval = expf(bv - m) / s;
                out_scores[(size_t)b * NN + row] = sval;
                out_labels[(size_t)b * NN + row] = (float)bc;
                scs[row] = sval;
                lab8[row] = (unsigned char)bc;
            }
        }
    }

    // ---- P0b: batch-0 keep flags (max over 80 logits > 0) ----
    const float4* row0 = (const float4*)(pc + (size_t)(NH - 1) * BB * NN * CC);
#pragma unroll
    for (int pass = 0; pass < 4; ++pass) {
        const int row = pass * 128 + quad;
        if (row < NN) {
            float m = -FLT_MAX;
#pragma unroll
            for (int k = 0; k < 5; ++k) {
                float4 v = row0[(size_t)row * 20 + q + 4 * k];
                m = fmaxf(m, fmaxf(fmaxf(v.x, v.y), fmaxf(v.z, v.w)));
            }
            m = fmaxf(m, __shfl_xor(m, 1));
            m = fmaxf(m, __shfl_xor(m, 2));
            if (q == 0) keepb[row] = (m > 0.0f) ? 1 : 0;
        }
    }

    // ---- P0c: boxes_start -> (x1,x2,w) ----
    float2 cw = make_float2(0.f, 0.f);
    if (tid < NN) {
        cw = ((const float2*)(pb + (size_t)(NH - 1) * BB * NN * 2))[(size_t)b * NN + tid];
        float w = fmaxf(cw.y, 0.0001f);
        box4u[tid] = make_float4(cw.x - w * 0.5f, cw.x + w * 0.5f, w, 0.f);
    }
    __syncthreads();

    // ---- P1: fused boxes_next ----
    if (tid < NN) {
        const size_t i = (size_t)b * NN + tid;
        int tn = t_now_p[0], tx = t_next_p[0];
        float a = ac[tn], an = ac[tx];
        float sqrt_recip = sqrtf(1.0f / a);
        float sqrt_recipm1 = sqrtf(1.0f / a - 1.0f);
        float sigma = sqrtf((1.0f - a / an) * (1.0f - an) / (1.0f - a));
        float ccf = sqrtf(1.0f - an - sigma * sigma);
        float sqan = sqrtf(an);
        const float2 bt = ((const float2*)boxes_t)[i];
        float2 o;
        if (keepb[tid]) {
            const float2 nz = ((const float2*)noise)[i];
            float pn0 = (sqrt_recip * bt.x - cw.x) / sqrt_recipm1;
            float pn1 = (sqrt_recip * bt.y - cw.y) / sqrt_recipm1;
            o.x = cw.x * sqan + ccf * pn0 + sigma * nz.x;
            o.y = cw.y * sqan + ccf * pn1 + sigma * nz.y;
        } else {
            o = ((const float2*)fresh)[i];
        }
        ((float2*)out_boxes)[i] = o;
    }

    // ---- P2: label-local rank (fused label+score scan) + histogram ----
    if (tid < NN) {
        const u32 myl = lab8[tid];
        const float si = scs[tid];
        int cnt = 0;
        const uint4* l16 = (const uint4*)lab8;
        for (int c = 0; c < NP / 16; ++c) {
            uint4 lv = l16[c];     // wave-uniform -> LDS broadcast
            const u32 lw[4] = {lv.x, lv.y, lv.z, lv.w};
            int base = c * 16;
#pragma unroll
            for (int g = 0; g < 4; ++g) {
                float4 s4 = scs4[c * 4 + g];
                int j0 = base + 4 * g;
                cnt += (((lw[g]      ) & 0xFFu) == myl) && ((s4.x > si) || (s4.x == si && (j0 + 0) < tid));
                cnt += (((lw[g] >>  8) & 0xFFu) == myl) && ((s4.y > si) || (s4.y == si && (j0 + 1) < tid));
                cnt += (((lw[g] >> 16) & 0xFFu) == myl) && ((s4.z > si) || (s4.z == si && (j0 + 2) < tid));
                cnt += (((lw[g] >> 24)        ) == myl) && ((s4.w > si) || (s4.w == si && (j0 + 3) < tid));
            }
        }
        brank_s[tid] = (short)cnt;
        atomicAdd(&hist[myl], 1);
    }
    __syncthreads();

    // ---- P2b: exclusive prefix over 80 bins (wave-0 shuffle scan) ----
    if (tid < 64) {
        int a = (tid < CC) ? hist[tid] : 0;
        int b2 = (tid < CC - 64) ? hist[64 + tid] : 0;
        int sa = a;
#pragma unroll
        for (int d = 1; d < 64; d <<= 1) {
            int t = __shfl_up(sa, d);
            if ((int)tid >= d) sa += t;
        }
        int totalA = __shfl(sa, 63);
        int sb = b2;
#pragma unroll
        for (int d = 1; d < 64; d <<= 1) {
            int t = __shfl_up(sb, d);
            if ((int)tid >= d) sb += t;
        }
        if (tid < CC) boff[tid] = sa - a;
        if (tid < CC - 64) boff[64 + tid] = sb - b2 + totalA;
    }
    __syncthreads();

    if (tid < NN) member[boff[lab8[tid]] + brank_s[tid]] = (short)tid;
    __syncthreads();

    // ---- P3: wave-per-bucket register greedy ----
    {
        const int wv = tid >> 6;
        const int lane = tid & 63;
        for (int l = wv; l < CC; l += 8) {
            const int n = hist[l];          // wave-uniform
            if (n <= 1) continue;
            const int off = boff[l];
            if (n <= 64) {
                const bool valid = lane < n;
                int rq = 0;
                float x1 = 0.f, x2 = 0.f, ww = 0.f;
                if (valid) {
                    rq = member[off + lane];
                    float4 v = box4u[rq];
                    x1 = v.x; x2 = v.y; ww = v.z;
                }
                bool sup = false;
                for (int p = 0; p < n - 1; ++p) {
                    u64 smask = __ballot(sup);
                    bool pAlive = ((smask >> p) & 1ull) == 0ull;
                    float bx1 = __int_as_float(__builtin_amdgcn_readlane(__float_as_int(x1), p));
                    float bx2 = __int_as_float(__builtin_amdgcn_readlane(__float_as_int(x2), p));
                    float bw  = __int_as_float(__builtin_amdgcn_readlane(__float_as_int(ww), p));
                    float inter = fmaxf(0.0f, fminf(bx2, x2) - fmaxf(bx1, x1));
                    float uni = bw + ww - inter;
                    float iou = inter / fmaxf(uni, 1e-9f);  // IEEE div, matches ref
                    sup = sup || (pAlive && valid && (lane > p) && (iou > 0.5f));
                }
                if (valid && sup) supp[rq] = 1;
            } else {
                if (lane == 0) {   // generic fallback, never triggers here
                    for (int p = 0; p < n - 1; ++p) {
                        int rp = member[off + p];
                        if (supp[rp]) continue;
                        float4 bp = box4u[rp];
                        for (int q2 = p + 1; q2 < n; ++q2) {
                            int rqq = member[off + q2];
                            if (supp[rqq]) continue;
                            float4 bq = box4u[rqq];
                            float inter = fmaxf(0.0f, fminf(bp.y, bq.y) - fmaxf(bp.x, bq.x));
                            float uni = bp.z + bq.z - inter;
                            float iou = inter / fmaxf(uni, 1e-9f);
                            if (iou > 0.5f) supp[rqq] = 1;
                        }
                    }
                }
            }
        }
    }
    __syncthreads();

    // ---- P4: coalesced final write (original id order) ----
    if (tid < NN) {
        out_keep[(size_t)b * NN + tid] = supp[tid] ? 0.0f : 1.0f;
    }
}

extern "C" void kernel_launch(void* const* d_in, const int* in_sizes, int n_in,
                              void* d_out, int out_size, void* d_ws, size_t ws_size,
                              hipStream_t stream) {
    const float* boxes_t = (const float*)d_in[0];
    const float* pc      = (const float*)d_in[1];
    const float* pb      = (const float*)d_in[2];
    const float* noise   = (const float*)d_in[3];
    const float* fresh   = (const float*)d_in[4];
    const float* ac      = (const float*)d_in[5];
    const int*   t_now   = (const int*)d_in[6];
    const int*   t_next  = (const int*)d_in[7];

    float* out_boxes  = (float*)d_out;                    // 128000
    float* out_scores = out_boxes + (size_t)BB * NN * 2;  // 64000
    float* out_labels = out_scores + (size_t)BB * NN;     // 64000
    float* out_keep   = out_labels + (size_t)BB * NN;     // 64000

    fused_kernel<<<BB, 512, 0, stream>>>(boxes_t, pc, pb, noise, fresh, ac,
                                         t_now, t_next,
                                         out_boxes, out_scores, out_labels, out_keep);
}

// Round 7
// 192.829 us; speedup vs baseline: 1.1368x; 1.1368x over previous
//
#include <hip/hip_runtime.h>
#include <float.h>

#define BB 128
#define NN 500
#define CC 80
#define NH 6
#define NP 512

typedef unsigned long long u64;
typedef unsigned int u32;

// ---------------------------------------------------------------------------
// scores/labels/keep fused. 4 threads per row, float4 loads. (R5, proven)
// ---------------------------------------------------------------------------
__global__ __launch_bounds__(256) void scores_labels_keep_kernel(
    const float* __restrict__ pc,
    float* __restrict__ scores,
    float* __restrict__ labels,
    int* __restrict__ keep) {
    const int rl = threadIdx.x >> 2;
    const int q = threadIdx.x & 3;
    const int row = blockIdx.x * 64 + rl;
    if (row >= BB * NN) return;

    const float4* base = (const float4*)(pc + (size_t)(NH - 1) * BB * NN * CC);
    float4 v[5];
#pragma unroll
    for (int k = 0; k < 5; ++k) v[k] = base[(size_t)row * 20 + q + 4 * k];

    float m = v[0].x;
#pragma unroll
    for (int k = 0; k < 5; ++k) {
        m = fmaxf(m, v[k].x); m = fmaxf(m, v[k].y);
        m = fmaxf(m, v[k].z); m = fmaxf(m, v[k].w);
    }
    m = fmaxf(m, __shfl_xor(m, 1));
    m = fmaxf(m, __shfl_xor(m, 2));

    float s = 0.0f;
#pragma unroll
    for (int k = 0; k < 5; ++k) {
        s += expf(v[k].x - m); s += expf(v[k].y - m);
        s += expf(v[k].z - m); s += expf(v[k].w - m);
    }
    s += __shfl_xor(s, 1);
    s += __shfl_xor(s, 2);

    float bv = -FLT_MAX; int bc = 1000;
#pragma unroll
    for (int k = 0; k < 5; ++k) {
        const float* vf = (const float*)&v[k];
#pragma unroll
        for (int j = 0; j < 4; ++j) {
            int c = (q + 4 * k) * 4 + j;
            float val = vf[j];
            if (c < CC - 1 && (val > bv || (val == bv && c < bc))) { bv = val; bc = c; }
        }
    }
#pragma unroll
    for (int off = 1; off < 4; off <<= 1) {
        float ov = __shfl_xor(bv, off);
        int oc = __shfl_xor(bc, off);
        if (ov > bv || (ov == bv && oc < bc)) { bv = ov; bc = oc; }
    }

    if (q == 0) {
        scores[row] = expf(bv - m) / s;
        labels[row] = (float)bc;
        if (row < NN) keep[row] = (m > 0.0f) ? 1 : 0;
    }
}

// ---------------------------------------------------------------------------
// NMS v6 + fused boxes_next. One block (512 threads, 8 waves) per batch.
// NO global sort, NO rank scans:
//  P0 : load boxes/scores/labels; fused boxes_next
//  P1 : LDS histogram (1 atomic/thread)
//  P2 : wave-0 shuffle prefix -> cur = exclusive bucket offsets
//  P3 : arrival-order placement (1 atomic/thread) -> member lists
//  P4 : wave-per-bucket: members in lanes; (score desc, id asc) rank via
//       readlane loop; ds_permute push-to-rank-lane reorder; readlane/ballot
//       register greedy. Per-label greedy in label-local score order ==
//       reference global-order greedy (suppression couples same-label only).
//  P5 : coalesced keep_out write (original id order)
// ---------------------------------------------------------------------------
__global__ __launch_bounds__(512) void nms_kernel(const float* __restrict__ pb,
                                                  const float* __restrict__ scores,
                                                  const float* __restrict__ labels,
                                                  const float* __restrict__ boxes_t,
                                                  const float* __restrict__ noise,
                                                  const float* __restrict__ fresh,
                                                  const float* __restrict__ ac,
                                                  const int* __restrict__ t_now_p,
                                                  const int* __restrict__ t_next_p,
                                                  const int* __restrict__ keep_ws,
                                                  float* __restrict__ out_boxes,
                                                  float* __restrict__ keep_out) {
    __shared__ float4 box4u[NP];          // (x1,x2,w,score) by original id
    __shared__ short member[NP];          // bucket lists, arrival order
    __shared__ int hist[CC];
    __shared__ int cur[CC];
    __shared__ unsigned char supp[NP];

    const int b = blockIdx.x;
    const int tid = threadIdx.x;

    const float2* boxes = (const float2*)(pb + (size_t)(NH - 1) * BB * NN * 2) + (size_t)b * NN;
    const float* sc = scores + (size_t)b * NN;
    const float* lb = labels + (size_t)b * NN;

    // P0: prep + fused boxes_next
    if (tid < CC) hist[tid] = 0;
    supp[tid] = 0;
    int myl = -1;
    if (tid < NN) {
        float2 cw = boxes[tid];
        float w = fmaxf(cw.y, 0.0001f);
        myl = (int)lb[tid];
        box4u[tid] = make_float4(cw.x - w * 0.5f, cw.x + w * 0.5f, w, sc[tid]);

        // ---- fused boxes_next ----
        const size_t i = (size_t)b * NN + tid;
        int tn = t_now_p[0], tx = t_next_p[0];
        float a = ac[tn], an = ac[tx];
        float sqrt_recip = sqrtf(1.0f / a);
        float sqrt_recipm1 = sqrtf(1.0f / a - 1.0f);
        float sigma = sqrtf((1.0f - a / an) * (1.0f - an) / (1.0f - a));
        float ccf = sqrtf(1.0f - an - sigma * sigma);
        float sqan = sqrtf(an);
        const float2 bt = ((const float2*)boxes_t)[i];
        float2 o;
        if (keep_ws[tid]) {
            const float2 nz = ((const float2*)noise)[i];
            float pn0 = (sqrt_recip * bt.x - cw.x) / sqrt_recipm1;
            float pn1 = (sqrt_recip * bt.y - cw.y) / sqrt_recipm1;
            o.x = cw.x * sqan + ccf * pn0 + sigma * nz.x;
            o.y = cw.y * sqan + ccf * pn1 + sigma * nz.y;
        } else {
            o = ((const float2*)fresh)[i];
        }
        ((float2*)out_boxes)[i] = o;
    }
    __syncthreads();

    // P1: histogram
    if (tid < NN) atomicAdd(&hist[myl], 1);
    __syncthreads();

    // P2: exclusive prefix over 80 bins (wave-0 shuffle scan) -> cur
    if (tid < 64) {
        int a = (tid < CC) ? hist[tid] : 0;
        int b2 = (tid < CC - 64) ? hist[64 + tid] : 0;
        int sa = a;
#pragma unroll
        for (int d = 1; d < 64; d <<= 1) {
            int t = __shfl_up(sa, d);
            if ((int)tid >= d) sa += t;
        }
        int totalA = __shfl(sa, 63);
        int sb = b2;
#pragma unroll
        for (int d = 1; d < 64; d <<= 1) {
            int t = __shfl_up(sb, d);
            if ((int)tid >= d) sb += t;
        }
        if (tid < CC) cur[tid] = sa - a;
        if (tid < CC - 64) cur[64 + tid] = sb - b2 + totalA;
    }
    __syncthreads();

    // P3: arrival-order placement
    if (tid < NN) {
        int pos = atomicAdd(&cur[myl], 1);
        member[pos] = (short)tid;
    }
    __syncthreads();
    // note: cur[l] is now boff[l] + hist[l]

    // P4: wave-per-bucket register greedy
    {
        const int wv = tid >> 6;
        const int lane = tid & 63;
        for (int l = wv; l < CC; l += 8) {
            const int n = hist[l];          // wave-uniform
            if (n <= 1) continue;
            const int off = cur[l] - n;
            if (n <= 64) {
                const bool valid = lane < n;
                int id = valid ? (int)member[off + lane] : 0;
                float4 v = box4u[id];
                float sco = valid ? v.w : -FLT_MAX;
                int idk = valid ? id : 0x7FFFFFFF;
                // rank within bucket: (score desc, original id asc) — unique
                int r = 0;
                for (int p = 0; p < n; ++p) {
                    float sp = __int_as_float(__builtin_amdgcn_readlane(__float_as_int(sco), p));
                    int ip = __builtin_amdgcn_readlane(idk, p);
                    r += (sp > sco) || (sp == sco && ip < idk);
                }
                // push my data to my rank's lane (invalid lanes: identity)
                int tgt = (valid ? r : lane) << 2;
                float x1 = __int_as_float(__builtin_amdgcn_ds_permute(tgt, __float_as_int(v.x)));
                float x2 = __int_as_float(__builtin_amdgcn_ds_permute(tgt, __float_as_int(v.y)));
                float ww = __int_as_float(__builtin_amdgcn_ds_permute(tgt, __float_as_int(v.z)));
                int rid  = __builtin_amdgcn_ds_permute(tgt, id);
                // greedy in rank order
                bool sup = false;
                for (int p = 0; p < n - 1; ++p) {
                    u64 alive = __ballot(sup);
                    bool pAlive = ((alive >> p) & 1ull) == 0ull;
                    float bx1 = __int_as_float(__builtin_amdgcn_readlane(__float_as_int(x1), p));
                    float bx2 = __int_as_float(__builtin_amdgcn_readlane(__float_as_int(x2), p));
                    float bw  = __int_as_float(__builtin_amdgcn_readlane(__float_as_int(ww), p));
                    float inter = fmaxf(0.0f, fminf(bx2, x2) - fmaxf(bx1, x1));
                    float uni = bw + ww - inter;
                    float iou = inter / fmaxf(uni, 1e-9f);  // IEEE div, matches ref
                    sup = sup || (pAlive && valid && (lane > p) && (iou > 0.5f));
                }
                if (valid && sup) supp[rid] = 1;
            } else {
                // correct fallback, never triggers for these inputs
                if (lane == 0) {
                    for (int step = 0; step < n; ++step) {
                        int bi = -1, bid = 0x7FFFFFFF; float bs = -FLT_MAX;
                        for (int k = 0; k < n; ++k) {
                            int id2 = member[off + k];
                            if (id2 < 0) continue;
                            float s2 = box4u[id2].w;
                            if (s2 > bs || (s2 == bs && id2 < bid)) { bs = s2; bid = id2; bi = k; }
                        }
                        if (bi < 0) break;
                        member[off + bi] = -1;
                        if (!supp[bid]) {
                            float4 bp = box4u[bid];
                            for (int k = 0; k < n; ++k) {
                                int id2 = member[off + k];
                                if (id2 < 0) continue;
                                float4 bq = box4u[id2];
                                float inter = fmaxf(0.0f, fminf(bp.y, bq.y) - fmaxf(bp.x, bq.x));
                                float uni = bp.z + bq.z - inter;
                                float iou = inter / fmaxf(uni, 1e-9f);
                                if (iou > 0.5f) supp[id2] = 1;
                            }
                        }
                    }
                }
            }
        }
    }
    __syncthreads();

    // P5: coalesced final write (original id order — no sort anywhere)
    if (tid < NN) {
        keep_out[(size_t)b * NN + tid] = supp[tid] ? 0.0f : 1.0f;
    }
}

extern "C" void kernel_launch(void* const* d_in, const int* in_sizes, int n_in,
                              void* d_out, int out_size, void* d_ws, size_t ws_size,
                              hipStream_t stream) {
    const float* boxes_t = (const float*)d_in[0];
    const float* pc      = (const float*)d_in[1];
    const float* pb      = (const float*)d_in[2];
    const float* noise   = (const float*)d_in[3];
    const float* fresh   = (const float*)d_in[4];
    const float* ac      = (const float*)d_in[5];
    const int*   t_now   = (const int*)d_in[6];
    const int*   t_next  = (const int*)d_in[7];

    float* out_boxes  = (float*)d_out;                    // 128000
    float* out_scores = out_boxes + (size_t)BB * NN * 2;  // 64000
    float* out_labels = out_scores + (size_t)BB * NN;     // 64000
    float* out_keep   = out_labels + (size_t)BB * NN;     // 64000

    int* keep_ws = (int*)d_ws;

    scores_labels_keep_kernel<<<(BB * NN) / 64, 256, 0, stream>>>(
        pc, out_scores, out_labels, keep_ws);
    nms_kernel<<<BB, 512, 0, stream>>>(pb, out_scores, out_labels,
                                       boxes_t, noise, fresh, ac, t_now, t_next,
                                       keep_ws, out_boxes, out_keep);
}